// Round 9
// baseline (303.968 us; speedup 1.0000x reference)
//
#include <hip/hip_runtime.h>
#include <hip/hip_bf16.h>
#include <math.h>

#define B_    2
#define T_    2048
#define CEMB  2048
#define NH    16
#define NKV   4
#define DHD   128
#define QKVD  3072   // CEMB + 2*NKV*DHD

typedef unsigned short u16;
typedef unsigned int   u32;
typedef __attribute__((ext_vector_type(8))) short  short8;   // 8 bf16 = 4 VGPRs
typedef __attribute__((ext_vector_type(4))) float  floatx4;  // MFMA accumulator

static __device__ __forceinline__ u16 f2bf(float f){
    union{float f;u32 u;}x; x.f = f; u32 u = x.u;
    return (u16)((u + 0x7fffu + ((u >> 16) & 1u)) >> 16);
}
static __device__ __forceinline__ float lo2f(u32 w){ union{u32 u;float f;}x; x.u = w << 16; return x.f; }
static __device__ __forceinline__ float hi2f(u32 w){ union{u32 u;float f;}x; x.u = w & 0xffff0000u; return x.f; }

// Packed f32x2 -> bf16x2 RNE convert (1 VALU instr).
static __device__ __forceinline__ u32 cvt_pk_bf16(float lo, float hi){
    u32 r;
    asm("v_cvt_pk_bf16_f32 %0, %1, %2" : "=v"(r) : "v"(lo), "v"(hi));
    return r;
}

// Async global->LDS 16B copy: LDS dest is wave-uniform base + lane*16.
static __device__ __forceinline__ void async_cp16(const u16* g, u16* lds_wave_base) {
    __builtin_amdgcn_global_load_lds(
        (const __attribute__((address_space(1))) void*)g,
        (__attribute__((address_space(3))) void*)lds_wave_base, 16, 0, 0);
}

// ---------------------------------------------------------------------------
// f32 -> bf16 convert (no transpose), 8 elements/thread.
// ---------------------------------------------------------------------------
__global__ __launch_bounds__(256) void convert_kernel(const float* __restrict__ in,
                                                      u16* __restrict__ out, int n8)
{
    const int i = blockIdx.x * 256 + threadIdx.x;
    if (i >= n8) return;
    const float4* p = reinterpret_cast<const float4*>(in);
    float4 a = p[i * 2], b = p[i * 2 + 1];
    uint4 o;
    o.x = (u32)f2bf(a.x) | ((u32)f2bf(a.y) << 16);
    o.y = (u32)f2bf(a.z) | ((u32)f2bf(a.w) << 16);
    o.z = (u32)f2bf(b.x) | ((u32)f2bf(b.y) << 16);
    o.w = (u32)f2bf(b.z) | ((u32)f2bf(b.w) << 16);
    reinterpret_cast<uint4*>(out)[i] = o;
}

// ---------------------------------------------------------------------------
// R15 transpose v2: f32 [R][Cn] -> bf16 [Cn][R]. 32-col x 256-row tiles,
// float4 reads, bf16 LDS staging, uint4 (16 B/lane) coalesced writes.
// ---------------------------------------------------------------------------
__global__ __launch_bounds__(256) void transpose_f32_bf16(const float* __restrict__ in,
                                                          u16* __restrict__ out,
                                                          int R, int Cn)
{
    __shared__ u16 tl[64][36];                 // 4.6 KB, uint2-aligned stride
    const int t  = threadIdx.x;
    const int c0 = blockIdx.x << 5;            // 32 cols
    const int r0 = blockIdx.y << 8;            // 256 rows
    const int cg = t & 7;                      // col group (x4)
    const int rr = t >> 3;                     // 0..31
    #pragma unroll
    for (int p = 0; p < 4; ++p) {
        #pragma unroll
        for (int s = 0; s < 2; ++s) {
            const int row = p * 64 + s * 32 + rr;
            const float4 v = *reinterpret_cast<const float4*>(
                &in[(size_t)(r0 + row) * Cn + c0 + cg * 4]);
            uint2 w;
            w.x = (u32)f2bf(v.x) | ((u32)f2bf(v.y) << 16);
            w.y = (u32)f2bf(v.z) | ((u32)f2bf(v.w) << 16);
            *reinterpret_cast<uint2*>(&tl[s * 32 + rr][cg * 4]) = w;
        }
        __syncthreads();
        {
            const int c = rr, j = cg;          // 32 cols x 8 r-groups
            u32 o0 = (u32)tl[j*8+0][c] | ((u32)tl[j*8+1][c] << 16);
            u32 o1 = (u32)tl[j*8+2][c] | ((u32)tl[j*8+3][c] << 16);
            u32 o2 = (u32)tl[j*8+4][c] | ((u32)tl[j*8+5][c] << 16);
            u32 o3 = (u32)tl[j*8+6][c] | ((u32)tl[j*8+7][c] << 16);
            uint4 o; o.x = o0; o.y = o1; o.z = o2; o.w = o3;
            *reinterpret_cast<uint4*>(&out[(size_t)(c0 + c) * R + r0 + p * 64 + j * 8]) = o;
        }
        __syncthreads();
    }
}

// ---------------------------------------------------------------------------
// R15 vt_build v2: vt[(b*NKV+kv)*DHD + d][T_] = qkv[t][2560+kv*128+d].
// uint2 reads, uint4 writes. Bit-exact data movement.
// ---------------------------------------------------------------------------
__global__ __launch_bounds__(256) void vt_build_kernel(const u16* __restrict__ qkv,
                                                       u16* __restrict__ vt)
{
    __shared__ u16 tl[64][36];
    const int t  = threadIdx.x;
    const int t0 = blockIdx.x << 8;            // 256 tokens
    const int d0 = blockIdx.y << 5;            // 32 d
    const int b  = blockIdx.z >> 2, kv = blockIdx.z & 3;
    const int cg = t & 7;                      // d group (x4)
    const int rr = t >> 3;                     // 0..31
    const u16* src = qkv + CEMB + NKV * DHD + kv * DHD + d0;
    #pragma unroll
    for (int p = 0; p < 4; ++p) {
        #pragma unroll
        for (int s = 0; s < 2; ++s) {
            const int row = p * 64 + s * 32 + rr;
            uint2 v = *reinterpret_cast<const uint2*>(
                &src[(size_t)(b * T_ + t0 + row) * QKVD + cg * 4]);
            *reinterpret_cast<uint2*>(&tl[s * 32 + rr][cg * 4]) = v;
        }
        __syncthreads();
        {
            const int c = rr, j = cg;
            u32 o0 = (u32)tl[j*8+0][c] | ((u32)tl[j*8+1][c] << 16);
            u32 o1 = (u32)tl[j*8+2][c] | ((u32)tl[j*8+3][c] << 16);
            u32 o2 = (u32)tl[j*8+4][c] | ((u32)tl[j*8+5][c] << 16);
            u32 o3 = (u32)tl[j*8+6][c] | ((u32)tl[j*8+7][c] << 16);
            uint4 o; o.x = o0; o.y = o1; o.z = o2; o.w = o3;
            *reinterpret_cast<uint4*>(
                &vt[(size_t)((b * NKV + kv) * DHD + d0 + c) * T_ + t0 + p * 64 + j * 8]) = o;
        }
        __syncthreads();
    }
}

// ---------------------------------------------------------------------------
// R11 MFMA GEMM (frozen, best measured): 8-wave, BM=256, BK=64, dbuf LDS,
// counted vmcnt, T2 source-pre-swizzled LDS, T5 setprio, T1 XCD chunking.
// ---------------------------------------------------------------------------
template <int BN_, int WM_, int WN_, bool F32OUT>
__global__ __launch_bounds__(512, 2) void gemm_mfma8_kernel(const u16* __restrict__ A,
                                                            const u16* __restrict__ BT,
                                                            void* __restrict__ Cv,
                                                            int M, int N, int K)
{
    constexpr int BM = 256, BK = 64;
    constexpr int MR = BM / WM_ / 16;            // m-fragments per wave
    constexpr int NR = BN_ / WN_ / 16;           // n-fragments per wave
    constexpr int AR = (BM * BK * 2) / 8192;     // A stage rounds (512 thr x 16B) = 4
    constexpr int BR = (BN_ * BK * 2) / 8192;    // B stage rounds
    constexpr int LPT = AR + BR;                 // loads per thread per K-tile

    __shared__ __align__(16) u16 As[2][BM * BK];
    __shared__ __align__(16) u16 Bs[2][BN_ * BK];

    const int tid  = threadIdx.x;
    const int lane = tid & 63;
    const int wv   = tid >> 6;          // 0..7
    const int n16  = lane & 15;
    const int quad = lane >> 4;
    const int wm   = wv / WN_;
    const int wn   = wv % WN_;

    const int GX  = gridDim.x;
    const int nwg = GX * gridDim.y;
    const int lin = blockIdx.y * GX + blockIdx.x;
    const int swz = (lin & 7) * (nwg >> 3) + (lin >> 3);
    const int row0 = (swz / GX) * BM;
    const int col0 = (swz % GX) * BN_;

    auto stage = [&](int t, int buf) {
        const int k0 = t * BK;
        const int rA = tid >> 3;                 // row within a 64-row round
        const int lc = (tid & 7) ^ (rA & 7);     // logical chunk (k/8)
        #pragma unroll
        for (int r = 0; r < AR; ++r)
            async_cp16(A + (size_t)(row0 + r * 64 + rA) * K + k0 + (lc << 3),
                       &As[buf][(r * 512 + wv * 64) * 8]);
        #pragma unroll
        for (int r = 0; r < BR; ++r)
            async_cp16(BT + (size_t)(col0 + r * 64 + rA) * K + k0 + (lc << 3),
                       &Bs[buf][(r * 512 + wv * 64) * 8]);
    };

    floatx4 acc[MR][NR];
    #pragma unroll
    for (int m = 0; m < MR; ++m)
        #pragma unroll
        for (int n = 0; n < NR; ++n) acc[m][n] = (floatx4)0.0f;

    const int nt = K / BK;
    stage(0, 0);
    stage(1, 1);

    for (int t = 0; t < nt; ++t) {
        const int cur = t & 1;
        if (t + 1 < nt) asm volatile("s_waitcnt vmcnt(%0)" :: "i"(LPT) : "memory");
        else            asm volatile("s_waitcnt vmcnt(0)" ::: "memory");
        __builtin_amdgcn_s_barrier();

        const u16* as = As[cur];
        const u16* bs = Bs[cur];
        #pragma unroll
        for (int kh = 0; kh < 2; ++kh) {
            short8 af[MR], bf[NR];
            #pragma unroll
            for (int m = 0; m < MR; ++m) {
                const int row = wm * (BM / WM_) + m * 16 + n16;
                af[m] = *reinterpret_cast<const short8*>(
                    &as[row * BK + (((kh * 4 + quad) ^ (row & 7)) << 3)]);
            }
            #pragma unroll
            for (int n = 0; n < NR; ++n) {
                const int col = wn * (BN_ / WN_) + n * 16 + n16;
                bf[n] = *reinterpret_cast<const short8*>(
                    &bs[col * BK + (((kh * 4 + quad) ^ (col & 7)) << 3)]);
            }
            __builtin_amdgcn_s_setprio(1);
            #pragma unroll
            for (int m = 0; m < MR; ++m)
                #pragma unroll
                for (int n = 0; n < NR; ++n)
                    acc[m][n] = __builtin_amdgcn_mfma_f32_16x16x32_bf16(af[m], bf[n], acc[m][n], 0, 0, 0);
            __builtin_amdgcn_s_setprio(0);
        }

        asm volatile("s_waitcnt lgkmcnt(0)" ::: "memory");
        __builtin_amdgcn_s_barrier();
        __builtin_amdgcn_sched_barrier(0);
        if (t + 2 < nt) stage(t + 2, cur);
    }

    #pragma unroll
    for (int m = 0; m < MR; ++m) {
        #pragma unroll
        for (int r = 0; r < 4; ++r) {
            const int row = row0 + wm * (BM / WM_) + m * 16 + quad * 4 + r;
            if (F32OUT) {
                float* C = reinterpret_cast<float*>(Cv);
                #pragma unroll
                for (int n = 0; n < NR; ++n)
                    C[(size_t)row * N + col0 + wn * (BN_ / WN_) + n * 16 + n16] = acc[m][n][r];
            } else {
                u16* C = reinterpret_cast<u16*>(Cv);
                #pragma unroll
                for (int n = 0; n < NR; ++n)
                    C[(size_t)row * N + col0 + wn * (BN_ / WN_) + n * 16 + n16] = f2bf(acc[m][n][r]);
            }
        }
    }
}

// ---------------------------------------------------------------------------
// R15 RoPE / YaRN v2 (native __sinf/__cosf; verified passing).
// ---------------------------------------------------------------------------
__global__ __launch_bounds__(256) void rope_kernel(
    u16* __restrict__ qkv, const float attn_factor, const float low, const float high)
{
    const int total = B_ * T_ * (NH + NKV) * (DHD / 2);
    int idx = blockIdx.x * 256 + threadIdx.x;
    if (idx >= total) return;
    const int d = idx & 63;
    int r = idx >> 6;
    const int h = r % (NH + NKV);
    r /= (NH + NKV);
    const int t = r % T_;
    const int b = r / T_;
    const int off = (h < NH) ? (h * DHD) : (CEMB + (h - NH) * DHD);

    u32* p = reinterpret_cast<u32*>(qkv + (size_t)(b * T_ + t) * QKVD + off) + d;
    u32 w = *p;
    float xe = lo2f(w), xo = hi2f(w);

    float df   = (float)d;
    float ramp = fminf(fmaxf((df - low) / (high - low), 0.0f), 1.0f);
    float pf   = exp2f(df * 0.31143075889569f);   // base^(2d/128), base=1e6
    float inv  = (1.0f / pf) * ((1.0f / 64.0f) * ramp + (1.0f - ramp));
    float ang  = (float)t * inv;
    float s = __sinf(ang), c = __cosf(ang);
    float oe = (xe * c - xo * s) * attn_factor;
    float oo = (xe * s + xo * c) * attn_factor;
    *p = (u32)f2bf(oe) | ((u32)f2bf(oo) << 16);
}

// ---------------------------------------------------------------------------
// MFMA flash attention (causal, GQA). R16 (resubmitted — prior round was an
// infra failure, never measured): R10 structure with the P LDS round-trip
// replaced by IN-REGISTER P via shuffles:
//   After softmax, lane (quad,n16) holds pk[t] (bf16x2-packed P for keys
//   t*16+quad*4+{0..3}, query n16). PV's B-fragment kt needs keys
//   kt*32+quad*8+{0..7}: t_src = 2kt+(quad>>1), source lanes
//   ((quad&1)<<5)+n16 and +16, words x/y. 16 __shfl + 8 selects replace
//   4 ds_write_b64 + 2 ds_read_b128 + lgkm round-trip and kill Pl's
//   even-bank-only conflicts. Pl removed: LDS 81920 -> 65536 B.
//   P values bitwise identical.
// ---------------------------------------------------------------------------
__global__ __launch_bounds__(512, 4) void attn_mfma_kernel(const u16* __restrict__ qkv,
                                                           const u16* __restrict__ vt,
                                                           u16* __restrict__ y)
{
    __shared__ __align__(16) u16 Ksd[2][64 * 128];   // [buf][key][d]  (swizzled chunks)
    __shared__ __align__(16) u16 Vtsd[2][128 * 64];  // [buf][d][key]  (swizzled chunks)

    const int tid  = threadIdx.x;
    const int lane = tid & 63;
    const int wv   = tid >> 6;        // 0..7
    const int n16  = lane & 15;
    const int quad = lane >> 4;

    const int lin = blockIdx.y * 16 + blockIdx.x;   // 0..511, nwg%8==0 -> bijective
    const int swz = (lin & 7) * 64 + (lin >> 3);
    const int nx  = swz & 15;
    const int bh  = swz >> 4;
    const int b   = bh >> 4;
    const int h   = bh & 15;
    const int kh  = h >> 2;

    const float C1 = 0.08838834764831845f * 1.4426950408889634f;  // scale * log2(e)

    const u16* kbase = qkv + (size_t)(b * T_) * QKVD + CEMB + kh * DHD;
    const u16* vbase = vt + (size_t)((b * NKV + kh) * DHD) * T_;

    auto dma_k = [&](int j0, int buf) {
        #pragma unroll
        for (int it = 0; it < 2; ++it) {
            const int P   = it * 512 + tid;          // physical chunk 0..1023
            const int row = P >> 4;                  // key 0..63
            const int lc  = (P & 15) ^ (row & 15);   // logical chunk (d/8)
            async_cp16(kbase + (size_t)(j0 + row) * QKVD + (lc << 3),
                       &Ksd[buf][(it * 512 + wv * 64) * 8]);
        }
    };
    auto dma_v = [&](int j0, int buf) {
        #pragma unroll
        for (int it = 0; it < 2; ++it) {
            const int P   = it * 512 + tid;          // physical chunk 0..1023
            const int row = P >> 3;                  // d 0..127
            const int lc  = (P & 7) ^ (row & 7);     // logical chunk (key/8)
            async_cp16(vbase + (size_t)row * T_ + j0 + (lc << 3),
                       &Vtsd[buf][(it * 512 + wv * 64) * 8]);
        }
    };

    const int i0H = (31 - nx) << 6;                  // heavy bound (>= light)
    const int i0  = (wv < 4) ? i0H : (nx << 6);      // this wave's query tile
    const int qb  = i0 + (wv & 3) * 16;              // wave's first query row
    const int qrow = qb + n16;                       // lane's query

    const u16* qp = qkv + (size_t)(b * T_ + qrow) * QKVD + h * DHD;
    short8 qf[4];
    #pragma unroll
    for (int kk = 0; kk < 4; ++kk)
        qf[kk] = *reinterpret_cast<const short8*>(qp + kk * 32 + quad * 8);

    floatx4 oacc[8];
    #pragma unroll
    for (int i = 0; i < 8; ++i) oacc[i] = (floatx4)0.0f;
    float m_cur = -INFINITY, l_cur = 0.0f;

    // Shuffle constants for in-register P redistribution.
    const int srcA = ((quad & 1) << 5) + n16;   // lane holding words w0,w1
    const int srcB = srcA + 16;                 // lane holding words w2,w3
    const bool hiT = (quad >> 1) != 0;          // select t_src = 2kt+1

    dma_k(0, 0);
    dma_v(0, 0);

    for (int j0 = 0; j0 <= i0H; j0 += 64) {
        const int buf = (j0 >> 6) & 1;
        __syncthreads();             // drains this tile's DMA (vmcnt) + barrier
        if (j0 + 64 <= i0H) {        // DMA next tile; lands by the NEXT barrier
            dma_k(j0 + 64, buf ^ 1);
            dma_v(j0 + 64, buf ^ 1);
        }
        if (j0 > i0) continue;       // light waves done with useful keys (wave-uniform)

        const u16* kb = Ksd[buf];
        const u16* vb = Vtsd[buf];

        floatx4 st[4];
        #pragma unroll
        for (int t = 0; t < 4; ++t) st[t] = (floatx4)0.0f;
        __builtin_amdgcn_s_setprio(1);
        #pragma unroll
        for (int t = 0; t < 4; ++t) {
            #pragma unroll
            for (int kk = 0; kk < 4; ++kk) {
                short8 a = *reinterpret_cast<const short8*>(
                    &kb[(t * 16 + n16) * 128 + (((kk * 4 + quad) ^ n16) << 3)]);
                st[t] = __builtin_amdgcn_mfma_f32_16x16x32_bf16(a, qf[kk], st[t], 0, 0, 0);
            }
        }
        __builtin_amdgcn_s_setprio(0);

        const bool diag = (j0 + 63 > qb);
        float tmax = -INFINITY;
        #pragma unroll
        for (int t = 0; t < 4; ++t) {
            if (diag) {
                #pragma unroll
                for (int r = 0; r < 4; ++r) {
                    const int key = j0 + t * 16 + quad * 4 + r;
                    if (key > qrow) st[t][r] = -INFINITY;
                }
            }
            tmax = fmaxf(tmax,
                         fmaxf(fmaxf(st[t][0], st[t][1]), fmaxf(st[t][2], st[t][3])));
        }
        tmax = fmaxf(tmax, __shfl_xor(tmax, 16));
        tmax = fmaxf(tmax, __shfl_xor(tmax, 32));

        if (!__all((tmax - m_cur) * C1 <= 8.0f)) {
            const float mnew  = fmaxf(m_cur, tmax);
            const float alpha = exp2f((m_cur - mnew) * C1);
            m_cur = mnew;
            l_cur *= alpha;
            #pragma unroll
            for (int dt = 0; dt < 8; ++dt) {
                oacc[dt][0] *= alpha; oacc[dt][1] *= alpha;
                oacc[dt][2] *= alpha; oacc[dt][3] *= alpha;
            }
        }

        const float mC = m_cur * C1;
        float lsum = 0.0f;
        u32 pkx[4], pky[4];
        #pragma unroll
        for (int t = 0; t < 4; ++t) {
            float p0 = exp2f(fmaf(st[t][0], C1, -mC));
            float p1 = exp2f(fmaf(st[t][1], C1, -mC));
            float p2 = exp2f(fmaf(st[t][2], C1, -mC));
            float p3 = exp2f(fmaf(st[t][3], C1, -mC));
            lsum += (p0 + p1) + (p2 + p3);
            pkx[t] = cvt_pk_bf16(p0, p1);
            pky[t] = cvt_pk_bf16(p2, p3);
        }
        lsum += __shfl_xor(lsum, 16);
        lsum += __shfl_xor(lsum, 32);
        l_cur += lsum;

        // ---- O^T += V^T * P^T with in-register P via shuffles
        __builtin_amdgcn_s_setprio(1);
        #pragma unroll
        for (int kt = 0; kt < 2; ++kt) {
            const u32 a0 = (u32)__shfl((int)pkx[kt * 2],     srcA);
            const u32 a1 = (u32)__shfl((int)pky[kt * 2],     srcA);
            const u32 a2 = (u32)__shfl((int)pkx[kt * 2],     srcB);
            const u32 a3 = (u32)__shfl((int)pky[kt * 2],     srcB);
            const u32 b0 = (u32)__shfl((int)pkx[kt * 2 + 1], srcA);
            const u32 b1 = (u32)__shfl((int)pky[kt * 2 + 1], srcA);
            const u32 b2 = (u32)__shfl((int)pkx[kt * 2 + 1], srcB);
            const u32 b3 = (u32)__shfl((int)pky[kt * 2 + 1], srcB);
            u32 w[4];
            w[0] = hiT ? b0 : a0;
            w[1] = hiT ? b1 : a1;
            w[2] = hiT ? b2 : a2;
            w[3] = hiT ? b3 : a3;
            short8 pfrag = *reinterpret_cast<const short8*>(w);
            #pragma unroll
            for (int dt = 0; dt < 8; ++dt) {
                short8 vfrag = *reinterpret_cast<const short8*>(
                    &vb[(dt * 16 + n16) * 64 + (((kt * 4 + quad) ^ (n16 & 7)) << 3)]);
                oacc[dt] = __builtin_amdgcn_mfma_f32_16x16x32_bf16(vfrag, pfrag, oacc[dt], 0, 0, 0);
            }
        }
        __builtin_amdgcn_s_setprio(0);
    }

    const float linv = 1.0f / l_cur;
    u16* yp = y + (size_t)(b * T_ + qrow) * CEMB + h * DHD + quad * 4;
    #pragma unroll
    for (int dt = 0; dt < 8; ++dt) {
        float a0 = oacc[dt][0] * linv, a1 = oacc[dt][1] * linv;
        float a2 = oacc[dt][2] * linv, a3 = oacc[dt][3] * linv;
        u32 w0 = cvt_pk_bf16(a0, a1);
        u32 w1 = cvt_pk_bf16(a2, a3);
        *reinterpret_cast<u32*>(yp + dt * 16)     = w0;
        *reinterpret_cast<u32*>(yp + dt * 16 + 2) = w1;
    }
}

// ---------------------------------------------------------------------------
extern "C" void kernel_launch(void* const* d_in, const int* in_sizes, int n_in,
                              void* d_out, int out_size, void* d_ws, size_t ws_size,
                              hipStream_t stream) {
    const size_t NX   = (size_t)B_ * T_ * CEMB;     // 8,388,608
    const size_t NWQ  = (size_t)CEMB * QKVD;        // 6,291,456
    const size_t NWO  = (size_t)CEMB * CEMB;        // 4,194,304
    const size_t NQKV = (size_t)B_ * T_ * QKVD;     // 12,582,912
    const size_t NY   = NX;

    u16* qkv = (u16*)d_ws;
    u16* y   = qkv + NQKV;
    u16* xb  = y + NY;
    u16* wqT = xb + NX;
    u16* woT = wqT + NWQ;
    u16* vtb = xb;   // alias: xb dead after GEMM1; Vt needs 2.1M u16 <= 8.4M

    // --- input conversion (f32 -> bf16), weights transposed for BT GEMM
    convert_kernel<<<(int)(NX / 8 + 255) / 256, 256, 0, stream>>>((const float*)d_in[0], xb, (int)(NX / 8));
    transpose_f32_bf16<<<dim3(QKVD / 32, CEMB / 256), 256, 0, stream>>>((const float*)d_in[1], wqT, CEMB, QKVD);
    transpose_f32_bf16<<<dim3(CEMB / 32, CEMB / 256), 256, 0, stream>>>((const float*)d_in[2], woT, CEMB, CEMB);

    // --- GEMM1: qkv = x @ w_qkv (bf16 out). 256x192 tiles -> 16x16 = 256 wg.
    gemm_mfma8_kernel<192, 2, 4, false><<<dim3(QKVD / 192, (B_ * T_) / 256), 512, 0, stream>>>(
        xb, wqT, qkv, B_ * T_, QKVD, CEMB);

    // --- RoPE constants (host, double precision, mirrors numpy)
    const double two_pi = 6.283185307179586476925286766559;
    double corr4 = 128.0 * log(4096.0 / (4.0 * two_pi)) / (2.0 * log(1.0e6));
    double corr1 = 128.0 * log(4096.0 / (1.0 * two_pi)) / (2.0 * log(1.0e6));
    double lowd  = floor(corr4); if (lowd < 0.0) lowd = 0.0;
    double highd = ceil(corr1);  if (highd > 127.0) highd = 127.0;
    if (lowd == highd) highd += 0.001;
    float attn_factor = (float)(0.1 * log(64.0) + 1.0);

    const int rope_total = B_ * T_ * (NH + NKV) * (DHD / 2);
    rope_kernel<<<(rope_total + 255) / 256, 256, 0, stream>>>(
        qkv, attn_factor, (float)lowd, (float)highd);

    // --- V^T buffer (overwrites xb, which is no longer needed)
    vt_build_kernel<<<dim3(T_ / 256, DHD / 32, B_ * NKV), 256, 0, stream>>>(qkv, vtb);

    // --- flash attention -> y (bf16); R16 in-register P
    attn_mfma_kernel<<<dim3(T_ / 128, B_ * NH), 512, 0, stream>>>(qkv, vtb, y);

    // --- GEMM2: out = y @ w_o (f32 out). 256x128 tiles -> 16x16 = 256 wg.
    gemm_mfma8_kernel<128, 4, 2, true><<<dim3(CEMB / 128, (B_ * T_) / 256), 512, 0, stream>>>(
        y, woT, d_out, B_ * T_, CEMB, CEMB);
}

// Round 10
// 298.301 us; speedup vs baseline: 1.0190x; 1.0190x over previous
//
#include <hip/hip_runtime.h>
#include <hip/hip_bf16.h>
#include <math.h>

#define B_    2
#define T_    2048
#define CEMB  2048
#define NH    16
#define NKV   4
#define DHD   128
#define QKVD  3072   // CEMB + 2*NKV*DHD

typedef unsigned short u16;
typedef unsigned int   u32;
typedef __attribute__((ext_vector_type(8))) short  short8;   // 8 bf16 = 4 VGPRs
typedef __attribute__((ext_vector_type(4))) float  floatx4;  // MFMA accumulator

static __device__ __forceinline__ u16 f2bf(float f){
    union{float f;u32 u;}x; x.f = f; u32 u = x.u;
    return (u16)((u + 0x7fffu + ((u >> 16) & 1u)) >> 16);
}
static __device__ __forceinline__ float lo2f(u32 w){ union{u32 u;float f;}x; x.u = w << 16; return x.f; }
static __device__ __forceinline__ float hi2f(u32 w){ union{u32 u;float f;}x; x.u = w & 0xffff0000u; return x.f; }

// Packed f32x2 -> bf16x2 RNE convert (1 VALU instr).
static __device__ __forceinline__ u32 cvt_pk_bf16(float lo, float hi){
    u32 r;
    asm("v_cvt_pk_bf16_f32 %0, %1, %2" : "=v"(r) : "v"(lo), "v"(hi));
    return r;
}

// Async global->LDS 16B copy: LDS dest is wave-uniform base + lane*16.
static __device__ __forceinline__ void async_cp16(const u16* g, u16* lds_wave_base) {
    __builtin_amdgcn_global_load_lds(
        (const __attribute__((address_space(1))) void*)g,
        (__attribute__((address_space(3))) void*)lds_wave_base, 16, 0, 0);
}

// ---------------------------------------------------------------------------
// f32 -> bf16 convert (no transpose), 8 elements/thread.
// ---------------------------------------------------------------------------
__global__ __launch_bounds__(256) void convert_kernel(const float* __restrict__ in,
                                                      u16* __restrict__ out, int n8)
{
    const int i = blockIdx.x * 256 + threadIdx.x;
    if (i >= n8) return;
    const float4* p = reinterpret_cast<const float4*>(in);
    float4 a = p[i * 2], b = p[i * 2 + 1];
    uint4 o;
    o.x = (u32)f2bf(a.x) | ((u32)f2bf(a.y) << 16);
    o.y = (u32)f2bf(a.z) | ((u32)f2bf(a.w) << 16);
    o.z = (u32)f2bf(b.x) | ((u32)f2bf(b.y) << 16);
    o.w = (u32)f2bf(b.z) | ((u32)f2bf(b.w) << 16);
    reinterpret_cast<uint4*>(out)[i] = o;
}

// ---------------------------------------------------------------------------
// R15 transpose v2: f32 [R][Cn] -> bf16 [Cn][R]. 32-col x 256-row tiles,
// float4 reads, bf16 LDS staging, uint4 (16 B/lane) coalesced writes.
// ---------------------------------------------------------------------------
__global__ __launch_bounds__(256) void transpose_f32_bf16(const float* __restrict__ in,
                                                          u16* __restrict__ out,
                                                          int R, int Cn)
{
    __shared__ u16 tl[64][36];                 // 4.6 KB, uint2-aligned stride
    const int t  = threadIdx.x;
    const int c0 = blockIdx.x << 5;            // 32 cols
    const int r0 = blockIdx.y << 8;            // 256 rows
    const int cg = t & 7;                      // col group (x4)
    const int rr = t >> 3;                     // 0..31
    #pragma unroll
    for (int p = 0; p < 4; ++p) {
        #pragma unroll
        for (int s = 0; s < 2; ++s) {
            const int row = p * 64 + s * 32 + rr;
            const float4 v = *reinterpret_cast<const float4*>(
                &in[(size_t)(r0 + row) * Cn + c0 + cg * 4]);
            uint2 w;
            w.x = (u32)f2bf(v.x) | ((u32)f2bf(v.y) << 16);
            w.y = (u32)f2bf(v.z) | ((u32)f2bf(v.w) << 16);
            *reinterpret_cast<uint2*>(&tl[s * 32 + rr][cg * 4]) = w;
        }
        __syncthreads();
        {
            const int c = rr, j = cg;          // 32 cols x 8 r-groups
            u32 o0 = (u32)tl[j*8+0][c] | ((u32)tl[j*8+1][c] << 16);
            u32 o1 = (u32)tl[j*8+2][c] | ((u32)tl[j*8+3][c] << 16);
            u32 o2 = (u32)tl[j*8+4][c] | ((u32)tl[j*8+5][c] << 16);
            u32 o3 = (u32)tl[j*8+6][c] | ((u32)tl[j*8+7][c] << 16);
            uint4 o; o.x = o0; o.y = o1; o.z = o2; o.w = o3;
            *reinterpret_cast<uint4*>(&out[(size_t)(c0 + c) * R + r0 + p * 64 + j * 8]) = o;
        }
        __syncthreads();
    }
}

// ---------------------------------------------------------------------------
// R15 vt_build v2: vt[(b*NKV+kv)*DHD + d][T_] = qkv[t][2560+kv*128+d].
// uint2 reads, uint4 writes. Bit-exact data movement.
// ---------------------------------------------------------------------------
__global__ __launch_bounds__(256) void vt_build_kernel(const u16* __restrict__ qkv,
                                                       u16* __restrict__ vt)
{
    __shared__ u16 tl[64][36];
    const int t  = threadIdx.x;
    const int t0 = blockIdx.x << 8;            // 256 tokens
    const int d0 = blockIdx.y << 5;            // 32 d
    const int b  = blockIdx.z >> 2, kv = blockIdx.z & 3;
    const int cg = t & 7;                      // d group (x4)
    const int rr = t >> 3;                     // 0..31
    const u16* src = qkv + CEMB + NKV * DHD + kv * DHD + d0;
    #pragma unroll
    for (int p = 0; p < 4; ++p) {
        #pragma unroll
        for (int s = 0; s < 2; ++s) {
            const int row = p * 64 + s * 32 + rr;
            uint2 v = *reinterpret_cast<const uint2*>(
                &src[(size_t)(b * T_ + t0 + row) * QKVD + cg * 4]);
            *reinterpret_cast<uint2*>(&tl[s * 32 + rr][cg * 4]) = v;
        }
        __syncthreads();
        {
            const int c = rr, j = cg;
            u32 o0 = (u32)tl[j*8+0][c] | ((u32)tl[j*8+1][c] << 16);
            u32 o1 = (u32)tl[j*8+2][c] | ((u32)tl[j*8+3][c] << 16);
            u32 o2 = (u32)tl[j*8+4][c] | ((u32)tl[j*8+5][c] << 16);
            u32 o3 = (u32)tl[j*8+6][c] | ((u32)tl[j*8+7][c] << 16);
            uint4 o; o.x = o0; o.y = o1; o.z = o2; o.w = o3;
            *reinterpret_cast<uint4*>(
                &vt[(size_t)((b * NKV + kv) * DHD + d0 + c) * T_ + t0 + p * 64 + j * 8]) = o;
        }
        __syncthreads();
    }
}

// ---------------------------------------------------------------------------
// R17 MFMA GEMM = frozen R11 structure (8-wave, BM=256, BK=64, dbuf LDS,
// counted vmcnt, T2 source-pre-swizzled LDS, T5 setprio, T1 XCD chunking)
// + OPTIONAL fused RoPE epilogue (ROPE template flag, GEMM1 only):
//   Columns < 2560 (q + k) are rotated IN THE EPILOGUE, on f32 accumulators,
//   before the bf16 store. Pair (col, col^1) lives in lanes (n16, n16^1) of
//   the same fragment (col = col0 + wn*(BN/WN) + n*16 + n16; all non-n16
//   terms even) -> partner value = __shfl_xor(v, 1). col<2560 test is
//   wave-uniform (2560 % 16 == 0). Eliminates the separate rope kernel:
//   one launch + 21 MB read + 21 MB write of q/k gone. Rotation happens
//   pre-rounding (closer to f32 reference than the old bf16-in-place rope).
// ---------------------------------------------------------------------------
template <int BN_, int WM_, int WN_, bool F32OUT, bool ROPE>
__global__ __launch_bounds__(512, 2) void gemm_mfma8_kernel(const u16* __restrict__ A,
                                                            const u16* __restrict__ BT,
                                                            void* __restrict__ Cv,
                                                            int M, int N, int K,
                                                            float rlow, float rhigh, float raf)
{
    constexpr int BM = 256, BK = 64;
    constexpr int MR = BM / WM_ / 16;            // m-fragments per wave
    constexpr int NR = BN_ / WN_ / 16;           // n-fragments per wave
    constexpr int AR = (BM * BK * 2) / 8192;     // A stage rounds (512 thr x 16B) = 4
    constexpr int BR = (BN_ * BK * 2) / 8192;    // B stage rounds
    constexpr int LPT = AR + BR;                 // loads per thread per K-tile

    __shared__ __align__(16) u16 As[2][BM * BK];
    __shared__ __align__(16) u16 Bs[2][BN_ * BK];

    const int tid  = threadIdx.x;
    const int lane = tid & 63;
    const int wv   = tid >> 6;          // 0..7
    const int n16  = lane & 15;
    const int quad = lane >> 4;
    const int wm   = wv / WN_;
    const int wn   = wv % WN_;

    const int GX  = gridDim.x;
    const int nwg = GX * gridDim.y;
    const int lin = blockIdx.y * GX + blockIdx.x;
    const int swz = (lin & 7) * (nwg >> 3) + (lin >> 3);
    const int row0 = (swz / GX) * BM;
    const int col0 = (swz % GX) * BN_;

    auto stage = [&](int t, int buf) {
        const int k0 = t * BK;
        const int rA = tid >> 3;                 // row within a 64-row round
        const int lc = (tid & 7) ^ (rA & 7);     // logical chunk (k/8)
        #pragma unroll
        for (int r = 0; r < AR; ++r)
            async_cp16(A + (size_t)(row0 + r * 64 + rA) * K + k0 + (lc << 3),
                       &As[buf][(r * 512 + wv * 64) * 8]);
        #pragma unroll
        for (int r = 0; r < BR; ++r)
            async_cp16(BT + (size_t)(col0 + r * 64 + rA) * K + k0 + (lc << 3),
                       &Bs[buf][(r * 512 + wv * 64) * 8]);
    };

    floatx4 acc[MR][NR];
    #pragma unroll
    for (int m = 0; m < MR; ++m)
        #pragma unroll
        for (int n = 0; n < NR; ++n) acc[m][n] = (floatx4)0.0f;

    const int nt = K / BK;
    stage(0, 0);
    stage(1, 1);

    for (int t = 0; t < nt; ++t) {
        const int cur = t & 1;
        if (t + 1 < nt) asm volatile("s_waitcnt vmcnt(%0)" :: "i"(LPT) : "memory");
        else            asm volatile("s_waitcnt vmcnt(0)" ::: "memory");
        __builtin_amdgcn_s_barrier();

        const u16* as = As[cur];
        const u16* bs = Bs[cur];
        #pragma unroll
        for (int kh = 0; kh < 2; ++kh) {
            short8 af[MR], bf[NR];
            #pragma unroll
            for (int m = 0; m < MR; ++m) {
                const int row = wm * (BM / WM_) + m * 16 + n16;
                af[m] = *reinterpret_cast<const short8*>(
                    &as[row * BK + (((kh * 4 + quad) ^ (row & 7)) << 3)]);
            }
            #pragma unroll
            for (int n = 0; n < NR; ++n) {
                const int col = wn * (BN_ / WN_) + n * 16 + n16;
                bf[n] = *reinterpret_cast<const short8*>(
                    &bs[col * BK + (((kh * 4 + quad) ^ (col & 7)) << 3)]);
            }
            __builtin_amdgcn_s_setprio(1);
            #pragma unroll
            for (int m = 0; m < MR; ++m)
                #pragma unroll
                for (int n = 0; n < NR; ++n)
                    acc[m][n] = __builtin_amdgcn_mfma_f32_16x16x32_bf16(af[m], bf[n], acc[m][n], 0, 0, 0);
            __builtin_amdgcn_s_setprio(0);
        }

        asm volatile("s_waitcnt lgkmcnt(0)" ::: "memory");
        __builtin_amdgcn_s_barrier();
        __builtin_amdgcn_sched_barrier(0);
        if (t + 2 < nt) stage(t + 2, cur);
    }

    #pragma unroll
    for (int m = 0; m < MR; ++m) {
        #pragma unroll
        for (int r = 0; r < 4; ++r) {
            const int row = row0 + wm * (BM / WM_) + m * 16 + quad * 4 + r;
            #pragma unroll
            for (int n = 0; n < NR; ++n) {
                const int col = col0 + wn * (BN_ / WN_) + n * 16 + n16;
                float v = acc[m][n][r];
                if (ROPE) {
                    // fused YaRN rotation on f32 acc (wave-uniform branch)
                    const float p = __shfl_xor(v, 1);     // partner col^1, all lanes
                    if (col < CEMB + NKV * DHD) {
                        const float df   = (float)((col & 127) >> 1);
                        float ramp = fminf(fmaxf((df - rlow) / (rhigh - rlow), 0.0f), 1.0f);
                        float pf   = exp2f(df * 0.31143075889569f);   // base^(2d/128)
                        float inv  = (1.0f / pf) * ((1.0f / 64.0f) * ramp + (1.0f - ramp));
                        float ang  = (float)(row & (T_ - 1)) * inv;
                        float s = __sinf(ang), c = __cosf(ang);
                        float sgn = (col & 1) ? s : -s;
                        v = (v * c + p * sgn) * raf;
                    }
                }
                if (F32OUT) reinterpret_cast<float*>(Cv)[(size_t)row * N + col] = v;
                else        reinterpret_cast<u16*>(Cv)[(size_t)row * N + col]   = f2bf(v);
            }
        }
    }
}

// ---------------------------------------------------------------------------
// MFMA flash attention (causal, GQA). REVERTED to R10 (best measured,
// 73.3-74.2 us): 8-wave blocks, heavy+light pairing, KVBLK=64, shared K/V
// dbuf, Pl stride-64 XOR-swz, XCD slab mapping, cvt_pk/defer-max/setprio.
// R12/R13/R16 restructures all regressed — this geometry is the floor;
// its Pl 2-way bank aliasing is free (m136).
// ---------------------------------------------------------------------------
__global__ __launch_bounds__(512, 4) void attn_mfma_kernel(const u16* __restrict__ qkv,
                                                           const u16* __restrict__ vt,
                                                           u16* __restrict__ y)
{
    __shared__ __align__(16) u16 Ksd[2][64 * 128];   // [buf][key][d]  (swizzled chunks)
    __shared__ __align__(16) u16 Vtsd[2][128 * 64];  // [buf][d][key]  (swizzled chunks)
    __shared__ __align__(16) u16 Pl[8 * 1024];       // per-wave P [16 q][64 k], XOR-swz

    const int tid  = threadIdx.x;
    const int lane = tid & 63;
    const int wv   = tid >> 6;        // 0..7
    const int n16  = lane & 15;
    const int quad = lane >> 4;

    const int lin = blockIdx.y * 16 + blockIdx.x;   // 0..511, nwg%8==0 -> bijective
    const int swz = (lin & 7) * 64 + (lin >> 3);
    const int nx  = swz & 15;
    const int bh  = swz >> 4;
    const int b   = bh >> 4;
    const int h   = bh & 15;
    const int kh  = h >> 2;

    const float C1 = 0.08838834764831845f * 1.4426950408889634f;  // scale * log2(e)

    u16* plw = Pl + wv * 1024;
    const int psw = (n16 & 7) << 3;   // Pl XOR swizzle (u16 units, bits 3-5)

    const u16* kbase = qkv + (size_t)(b * T_) * QKVD + CEMB + kh * DHD;
    const u16* vbase = vt + (size_t)((b * NKV + kh) * DHD) * T_;

    auto dma_k = [&](int j0, int buf) {
        #pragma unroll
        for (int it = 0; it < 2; ++it) {
            const int P   = it * 512 + tid;          // physical chunk 0..1023
            const int row = P >> 4;                  // key 0..63
            const int lc  = (P & 15) ^ (row & 15);   // logical chunk (d/8)
            async_cp16(kbase + (size_t)(j0 + row) * QKVD + (lc << 3),
                       &Ksd[buf][(it * 512 + wv * 64) * 8]);
        }
    };
    auto dma_v = [&](int j0, int buf) {
        #pragma unroll
        for (int it = 0; it < 2; ++it) {
            const int P   = it * 512 + tid;          // physical chunk 0..1023
            const int row = P >> 3;                  // d 0..127
            const int lc  = (P & 7) ^ (row & 7);     // logical chunk (key/8)
            async_cp16(vbase + (size_t)row * T_ + j0 + (lc << 3),
                       &Vtsd[buf][(it * 512 + wv * 64) * 8]);
        }
    };

    const int i0H = (31 - nx) << 6;                  // heavy bound (>= light)
    const int i0  = (wv < 4) ? i0H : (nx << 6);      // this wave's query tile
    const int qb  = i0 + (wv & 3) * 16;              // wave's first query row
    const int qrow = qb + n16;                       // lane's query

    const u16* qp = qkv + (size_t)(b * T_ + qrow) * QKVD + h * DHD;
    short8 qf[4];
    #pragma unroll
    for (int kk = 0; kk < 4; ++kk)
        qf[kk] = *reinterpret_cast<const short8*>(qp + kk * 32 + quad * 8);

    floatx4 oacc[8];
    #pragma unroll
    for (int i = 0; i < 8; ++i) oacc[i] = (floatx4)0.0f;
    float m_cur = -INFINITY, l_cur = 0.0f;

    dma_k(0, 0);
    dma_v(0, 0);

    for (int j0 = 0; j0 <= i0H; j0 += 64) {
        const int buf = (j0 >> 6) & 1;
        __syncthreads();             // drains this tile's DMA (vmcnt) + barrier
        if (j0 + 64 <= i0H) {        // DMA next tile; lands by the NEXT barrier
            dma_k(j0 + 64, buf ^ 1);
            dma_v(j0 + 64, buf ^ 1);
        }
        if (j0 > i0) continue;       // light waves done with useful keys (wave-uniform)

        const u16* kb = Ksd[buf];
        const u16* vb = Vtsd[buf];

        floatx4 st[4];
        #pragma unroll
        for (int t = 0; t < 4; ++t) st[t] = (floatx4)0.0f;
        __builtin_amdgcn_s_setprio(1);
        #pragma unroll
        for (int t = 0; t < 4; ++t) {
            #pragma unroll
            for (int kk = 0; kk < 4; ++kk) {
                short8 a = *reinterpret_cast<const short8*>(
                    &kb[(t * 16 + n16) * 128 + (((kk * 4 + quad) ^ n16) << 3)]);
                st[t] = __builtin_amdgcn_mfma_f32_16x16x32_bf16(a, qf[kk], st[t], 0, 0, 0);
            }
        }
        __builtin_amdgcn_s_setprio(0);

        const bool diag = (j0 + 63 > qb);
        float tmax = -INFINITY;
        #pragma unroll
        for (int t = 0; t < 4; ++t) {
            if (diag) {
                #pragma unroll
                for (int r = 0; r < 4; ++r) {
                    const int key = j0 + t * 16 + quad * 4 + r;
                    if (key > qrow) st[t][r] = -INFINITY;
                }
            }
            tmax = fmaxf(tmax,
                         fmaxf(fmaxf(st[t][0], st[t][1]), fmaxf(st[t][2], st[t][3])));
        }
        tmax = fmaxf(tmax, __shfl_xor(tmax, 16));
        tmax = fmaxf(tmax, __shfl_xor(tmax, 32));

        if (!__all((tmax - m_cur) * C1 <= 8.0f)) {
            const float mnew  = fmaxf(m_cur, tmax);
            const float alpha = exp2f((m_cur - mnew) * C1);
            m_cur = mnew;
            l_cur *= alpha;
            #pragma unroll
            for (int dt = 0; dt < 8; ++dt) {
                oacc[dt][0] *= alpha; oacc[dt][1] *= alpha;
                oacc[dt][2] *= alpha; oacc[dt][3] *= alpha;
            }
        }

        const float mC = m_cur * C1;
        float lsum = 0.0f;
        #pragma unroll
        for (int t = 0; t < 4; ++t) {
            float p0 = exp2f(fmaf(st[t][0], C1, -mC));
            float p1 = exp2f(fmaf(st[t][1], C1, -mC));
            float p2 = exp2f(fmaf(st[t][2], C1, -mC));
            float p3 = exp2f(fmaf(st[t][3], C1, -mC));
            lsum += (p0 + p1) + (p2 + p3);
            uint2 pk;
            pk.x = cvt_pk_bf16(p0, p1);
            pk.y = cvt_pk_bf16(p2, p3);
            *reinterpret_cast<uint2*>(&plw[n16 * 64 + ((t * 16 + quad * 4) ^ psw)]) = pk;
        }
        lsum += __shfl_xor(lsum, 16);
        lsum += __shfl_xor(lsum, 32);
        l_cur += lsum;

        __builtin_amdgcn_s_setprio(1);
        #pragma unroll
        for (int kt = 0; kt < 2; ++kt) {
            short8 pfrag = *reinterpret_cast<const short8*>(
                &plw[n16 * 64 + ((kt * 32 + quad * 8) ^ psw)]);
            #pragma unroll
            for (int dt = 0; dt < 8; ++dt) {
                short8 vfrag = *reinterpret_cast<const short8*>(
                    &vb[(dt * 16 + n16) * 64 + (((kt * 4 + quad) ^ (n16 & 7)) << 3)]);
                oacc[dt] = __builtin_amdgcn_mfma_f32_16x16x32_bf16(vfrag, pfrag, oacc[dt], 0, 0, 0);
            }
        }
        __builtin_amdgcn_s_setprio(0);
    }

    const float linv = 1.0f / l_cur;
    u16* yp = y + (size_t)(b * T_ + qrow) * CEMB + h * DHD + quad * 4;
    #pragma unroll
    for (int dt = 0; dt < 8; ++dt) {
        float a0 = oacc[dt][0] * linv, a1 = oacc[dt][1] * linv;
        float a2 = oacc[dt][2] * linv, a3 = oacc[dt][3] * linv;
        u32 w0 = cvt_pk_bf16(a0, a1);
        u32 w1 = cvt_pk_bf16(a2, a3);
        *reinterpret_cast<u32*>(yp + dt * 16)     = w0;
        *reinterpret_cast<u32*>(yp + dt * 16 + 2) = w1;
    }
}

// ---------------------------------------------------------------------------
extern "C" void kernel_launch(void* const* d_in, const int* in_sizes, int n_in,
                              void* d_out, int out_size, void* d_ws, size_t ws_size,
                              hipStream_t stream) {
    const size_t NX   = (size_t)B_ * T_ * CEMB;     // 8,388,608
    const size_t NWQ  = (size_t)CEMB * QKVD;        // 6,291,456
    const size_t NWO  = (size_t)CEMB * CEMB;        // 4,194,304
    const size_t NQKV = (size_t)B_ * T_ * QKVD;     // 12,582,912
    const size_t NY   = NX;

    u16* qkv = (u16*)d_ws;
    u16* y   = qkv + NQKV;
    u16* xb  = y + NY;
    u16* wqT = xb + NX;
    u16* woT = wqT + NWQ;
    u16* vtb = xb;   // alias: xb dead after GEMM1; Vt needs 2.1M u16 <= 8.4M

    // --- input conversion (f32 -> bf16), weights transposed for BT GEMM
    convert_kernel<<<(int)(NX / 8 + 255) / 256, 256, 0, stream>>>((const float*)d_in[0], xb, (int)(NX / 8));
    transpose_f32_bf16<<<dim3(QKVD / 32, CEMB / 256), 256, 0, stream>>>((const float*)d_in[1], wqT, CEMB, QKVD);
    transpose_f32_bf16<<<dim3(CEMB / 32, CEMB / 256), 256, 0, stream>>>((const float*)d_in[2], woT, CEMB, CEMB);

    // --- RoPE constants (host, double precision, mirrors numpy)
    const double two_pi = 6.283185307179586476925286766559;
    double corr4 = 128.0 * log(4096.0 / (4.0 * two_pi)) / (2.0 * log(1.0e6));
    double corr1 = 128.0 * log(4096.0 / (1.0 * two_pi)) / (2.0 * log(1.0e6));
    double lowd  = floor(corr4); if (lowd < 0.0) lowd = 0.0;
    double highd = ceil(corr1);  if (highd > 127.0) highd = 127.0;
    if (lowd == highd) highd += 0.001;
    float attn_factor = (float)(0.1 * log(64.0) + 1.0);

    // --- GEMM1: qkv = x @ w_qkv (bf16 out) with FUSED RoPE epilogue.
    //     256x192 tiles -> 16x16 = 256 wg (1 block/CU).
    gemm_mfma8_kernel<192, 2, 4, false, true><<<dim3(QKVD / 192, (B_ * T_) / 256), 512, 0, stream>>>(
        xb, wqT, qkv, B_ * T_, QKVD, CEMB, (float)lowd, (float)highd, attn_factor);

    // --- V^T buffer (overwrites xb, which is no longer needed)
    vt_build_kernel<<<dim3(T_ / 256, DHD / 32, B_ * NKV), 256, 0, stream>>>(qkv, vtb);

    // --- flash attention -> y (bf16); R10 8-wave heavy/light pairing
    attn_mfma_kernel<<<dim3(T_ / 128, B_ * NH), 512, 0, stream>>>(qkv, vtb, y);

    // --- GEMM2: out = y @ w_o (f32 out). 256x128 tiles -> 16x16 = 256 wg.
    gemm_mfma8_kernel<128, 4, 2, true, false><<<dim3(CEMB / 128, (B_ * T_) / 256), 512, 0, stream>>>(
        y, woT, d_out, B_ * T_, CEMB, CEMB, 0.0f, 0.0f, 0.0f);
}